// Round 7
// baseline (803.618 us; speedup 1.0000x reference)
//
#include <hip/hip_runtime.h>
#include <hip/hip_bf16.h>

// Problem constants (B,T,NI,NH,NO fixed by the reference)
constexpr int kB  = 64;
constexpr int kT  = 100;
constexpr int kNI = 700;
constexpr int kNH = 512;
constexpr int kNO = 20;
constexpr float TAU   = 0.6f;
constexpr float TAU_O = 0.6f;
constexpr float THR   = 0.6f;
constexpr float LR    = 0.05f;

constexpr size_t BNH = (size_t)kB * kNH;   // 32768
constexpr size_t BNI = (size_t)kB * kNI;   // 44800
constexpr size_t BNO = (size_t)kB * kNO;   // 1280
constexpr int kK   = kT * kB;              // 6400 (grad-GEMM K)
constexpr int kKP  = 704;                  // padded K for xw GEMM

typedef __attribute__((ext_vector_type(8))) short short8;
typedef __attribute__((ext_vector_type(4))) float f32x4;

// ---------------- workspace layout (float offsets) ---------------------------
// XW dead after k_forward -> PGF/PGR/PGO overlay it.
// HSUR dead after k_M2 -> TIB overlays it (castT(tin) launched after k_M2).
constexpr size_t O_XW   = 0;                                // [T, t*64+b, NH] 3,276,800
constexpr size_t O_PGF  = 0;                                // 4 x [512][768] = 1,572,864
constexpr size_t O_PGR  = 1572864;                          // 4 x [512][512] = 1,048,576
constexpr size_t O_PGO  = 2621440;                          // 8 x [20][512]  = 81,920 (ends 2,703,360)
constexpr size_t O_HSUR = 3276800;                          // [T,B,NH] 3,276,800
constexpr size_t O_TIB  = 3276800;                          // bf16 [700][6400] = 2,240,000 fl
constexpr size_t O_TIN  = 6553600;                          // [T,B,NI] 4,480,000
constexpr size_t O_HS   = 11033600;                         // [T+1,B,NH] 3,309,568 (row t = hs_{t-1})
constexpr size_t O_ERR  = 14343168;                         // [T,B,NO] 128,000
constexpr size_t O_WT   = 14471168;                         // [704,512] 360,448
constexpr size_t O_MTB  = 14831616;                         // bf16 [512][6400] = 1,638,400 fl
constexpr size_t O_TRB  = 16470016;                         // bf16 [512][6400] = 1,638,400 fl
constexpr size_t O_MSK  = 18108416;                         // u64 [T][B][8] = 102,400 fl
constexpr size_t WS_FLOATS = 18210816;                      // ~72.8 MB

// d_out layout
constexpr size_t OUT_GF = (size_t)kB * kT * kNO;
constexpr size_t OUT_GR = OUT_GF + (size_t)kNH * kNI;
constexpr size_t OUT_GO = OUT_GR + (size_t)kNH * kNH;

// ---- w_fc1 [NH,NI] -> wT [704,NH], rows 700..703 zero -----------------------
__global__ void k_transpose(const float* __restrict__ w, float* __restrict__ wT) {
    __shared__ float tile[32][33];
    int i0 = blockIdx.x * 32, r0 = blockIdx.y * 32;
    int tx = threadIdx.x, ty = threadIdx.y; // 32 x 8
    #pragma unroll
    for (int k = 0; k < 32; k += 8) {
        int i = i0 + tx;
        tile[ty + k][tx] = (i < kNI) ? w[(size_t)(r0 + ty + k) * kNI + i] : 0.f;
    }
    __syncthreads();
    #pragma unroll
    for (int k = 0; k < 32; k += 8) {
        int i = i0 + ty + k;
        wT[(size_t)i * kNH + r0 + tx] = tile[tx][ty + k];
    }
}

// ---- tin[t,b,i] = TAU*tin[t-1] + x[b,t,i] ----------------------------------
__global__ __launch_bounds__(256) void k_tin(const float* __restrict__ x, float* __restrict__ tin) {
    int idx = blockIdx.x * 256 + threadIdx.x;
    int b = idx / kNI, i = idx % kNI;
    const float* xp = x + (size_t)b * kT * kNI + i;
    float v = 0.f;
    for (int t = 0; t < kT; t++) {
        v = TAU * v + xp[(size_t)t * kNI];
        tin[(size_t)t * BNI + idx] = v;
    }
}

// ---- XW = Xperm @ wT : C[m=t*64+b, n<512], K=704 (fp32, exact) --------------
__global__ __launch_bounds__(256) void k_xw2(const float* __restrict__ x,
                                             const float* __restrict__ wT,
                                             float* __restrict__ XW) {
    int bx = blockIdx.x;
    int mt = bx % 50, nt = bx / 50;
    int m0 = mt * 128, n0 = nt * 128;
    int tid = threadIdx.x, tx = tid & 15, ty = tid >> 4;
    __shared__ float As[128][20];
    __shared__ float Bs[16][128];
    float acc[8][8] = {};
    int arow = tid >> 1, ahalf = tid & 1;
    int bb = (m0 + arow) & 63, tt = (m0 + arow) >> 6;
    const float* ap = x + ((size_t)bb * kT + tt) * kNI;
    for (int k0 = 0; k0 < kKP; k0 += 16) {
        #pragma unroll
        for (int u = 0; u < 2; u++) {
            int k = k0 + ahalf * 8 + u * 4;
            float4 v = (k + 3 < kNI) ? *(const float4*)(ap + k)
                                     : make_float4(0.f, 0.f, 0.f, 0.f);
            *(float4*)&As[arow][ahalf * 8 + u * 4] = v;
        }
        #pragma unroll
        for (int u = 0; u < 2; u++) {
            int f = tid * 2 + u;
            int kk = f >> 5, c4 = f & 31;
            *(float4*)&Bs[kk][c4 * 4] =
                *(const float4*)(wT + (size_t)(k0 + kk) * kNH + n0 + c4 * 4);
        }
        __syncthreads();
        #pragma unroll
        for (int kk = 0; kk < 16; kk++) {
            float av[8];
            #pragma unroll
            for (int i = 0; i < 4; i++) {
                av[i]     = As[ty * 4 + i][kk];
                av[4 + i] = As[64 + ty * 4 + i][kk];
            }
            float4 b0 = *(const float4*)&Bs[kk][tx * 4];
            float4 b1 = *(const float4*)&Bs[kk][64 + tx * 4];
            float bvv[8] = {b0.x, b0.y, b0.z, b0.w, b1.x, b1.y, b1.z, b1.w};
            #pragma unroll
            for (int i = 0; i < 8; i++)
                #pragma unroll
                for (int j = 0; j < 8; j++) acc[i][j] += av[i] * bvv[j];
        }
        __syncthreads();
    }
    #pragma unroll
    for (int i = 0; i < 8; i++) {
        int m = m0 + ((i < 4) ? (ty * 4 + i) : (64 + ty * 4 + i - 4));
        float* dst = XW + (size_t)m * kNH + n0;
        *(float4*)(dst + tx * 4)      = make_float4(acc[i][0], acc[i][1], acc[i][2], acc[i][3]);
        *(float4*)(dst + 64 + tx * 4) = make_float4(acc[i][4], acc[i][5], acc[i][6], acc[i][7]);
    }
}

// ---- fused forward: ONE block of 832 threads (13 waves) per sample ----------
// Waves 0-7: gather, wave w owns window [64w,64w+64). Mask walk extracts 4
// indices per group -> 8 b128 loads in flight (MLP vs serial chain).
// Waves 8-12: output LIF layer one step behind. 2 barriers/step.
__global__ __launch_bounds__(832) void k_forward(float* __restrict__ ws,
                                                 const float* __restrict__ label,
                                                 const float* __restrict__ w_rec,
                                                 const float* __restrict__ w_out,
                                                 float* __restrict__ dout,
                                                 unsigned long long* __restrict__ gmask) {
    __shared__ float wout_ld[kNO * kNH];          // 40 KB
    __shared__ float partial[8][kNH];             // 16 KB
    __shared__ unsigned long long mh[kT * 8];     // 6.4 KB mask history

    int b = blockIdx.x, tid = threadIdx.x;
    int wave = tid >> 6, lane = tid & 63;
    const f32x4* wr4 = (const f32x4*)w_rec;
    for (int e = tid; e < kNO * kNH; e += 832) wout_ld[e] = w_out[e];
    float hm = 0.f, sp_prev = 0.f;
    float om_r[4] = {0.f, 0.f, 0.f, 0.f}, os_r[4] = {0.f, 0.f, 0.f, 0.f};
    int q = wave - 8;
    const int coff = lane * 2;
    __syncthreads();

    for (int t = 0; t < kT; t++) {
        float xw = 0.f;
        if (wave < 8) {
            xw = ws[O_XW + ((size_t)t * 64 + b) * kNH + tid];
            unsigned long long m = (t > 0) ? mh[(t - 1) * 8 + wave] : 0ull;
            const size_t base = (size_t)wave * 64;
            f32x4 s0 = {0.f, 0.f, 0.f, 0.f}, s1 = s0, s2 = s0, s3 = s0;
            f32x4 s4 = s0, s5 = s0, s6 = s0, s7 = s0;
            int g4 = __popcll(m) >> 2;
            for (int g = 0; g < g4; g++) {
                int j0 = __builtin_ctzll(m); m &= m - 1;
                int j1 = __builtin_ctzll(m); m &= m - 1;
                int j2 = __builtin_ctzll(m); m &= m - 1;
                int j3 = __builtin_ctzll(m); m &= m - 1;
                const f32x4* r0 = wr4 + (base + j0) * 128 + coff;
                const f32x4* r1 = wr4 + (base + j1) * 128 + coff;
                const f32x4* r2 = wr4 + (base + j2) * 128 + coff;
                const f32x4* r3 = wr4 + (base + j3) * 128 + coff;
                f32x4 v0 = r0[0], v1 = r0[1];
                f32x4 v2 = r1[0], v3 = r1[1];
                f32x4 v4 = r2[0], v5 = r2[1];
                f32x4 v6 = r3[0], v7 = r3[1];
                s0 += v0; s1 += v1; s2 += v2; s3 += v3;
                s4 += v4; s5 += v5; s6 += v6; s7 += v7;
            }
            while (m) {
                int j = __builtin_ctzll(m); m &= m - 1;
                const f32x4* r = wr4 + (base + j) * 128 + coff;
                s0 += r[0]; s1 += r[1];
            }
            f32x4 ra = (s0 + s2) + (s4 + s6);
            f32x4 rb = (s1 + s3) + (s5 + s7);
            *(f32x4*)&partial[wave][lane * 8]     = ra;
            *(f32x4*)&partial[wave][lane * 8 + 4] = rb;
        } else if (t > 0) {
            // output LIF layer for step t-1 (wave q = 0..4)
            int to = t - 1;
            unsigned long long mk[8];
            #pragma unroll
            for (int k = 0; k < 8; k++) mk[k] = mh[to * 8 + k];
            #pragma unroll
            for (int r = 0; r < 4; r++) {
                int o = q * 4 + r;
                float p = 0.f;
                #pragma unroll
                for (int k = 0; k < 8; k++)
                    if ((mk[k] >> lane) & 1) p += wout_ld[o * kNH + 64 * k + lane];
                #pragma unroll
                for (int off = 32; off >= 1; off >>= 1) p += __shfl_xor(p, off);
                if (lane == 0) {
                    float om_n = TAU * om_r[r] * (1.f - os_r[r]) + p;
                    float os_n = (om_n >= THR) ? 1.f : 0.f;
                    om_r[r] = om_n; os_r[r] = os_n;
                    ws[O_ERR + (size_t)to * BNO + (size_t)b * kNO + o] =
                        os_n - label[((size_t)b * kT + to) * kNO + o];
                    dout[((size_t)b * kT + to) * kNO + o] = os_n;
                }
            }
        }
        __syncthreads();
        // ---- B: LIF update (threads < 512) ----
        if (tid < kNH) {
            float rec = ((partial[0][tid] + partial[1][tid]) + (partial[2][tid] + partial[3][tid]))
                      + ((partial[4][tid] + partial[5][tid]) + (partial[6][tid] + partial[7][tid]));
            hm = TAU * hm * (1.f - sp_prev) + (xw + rec);
            bool v = (hm >= THR);
            float sp = v ? 1.f : 0.f;
            sp_prev = sp;
            ws[O_HSUR + (size_t)t * BNH + (size_t)b * kNH + tid] =
                TAU * fmaxf(0.f, 1.f - fabsf(hm - THR) * (1.f / THR));
            unsigned long long bal = __ballot(v);
            if (lane == 0) {
                mh[t * 8 + wave] = bal;
                gmask[((size_t)t * 64 + b) * 8 + wave] = bal;
            }
        }
        __syncthreads();
    }
    // tail: output layer for t = 99
    if (wave >= 8) {
        int to = kT - 1;
        unsigned long long mk[8];
        #pragma unroll
        for (int k = 0; k < 8; k++) mk[k] = mh[to * 8 + k];
        #pragma unroll
        for (int r = 0; r < 4; r++) {
            int o = q * 4 + r;
            float p = 0.f;
            #pragma unroll
            for (int k = 0; k < 8; k++)
                if ((mk[k] >> lane) & 1) p += wout_ld[o * kNH + 64 * k + lane];
            #pragma unroll
            for (int off = 32; off >= 1; off >>= 1) p += __shfl_xor(p, off);
            if (lane == 0) {
                float om_n = TAU * om_r[r] * (1.f - os_r[r]) + p;
                float os_n = (om_n >= THR) ? 1.f : 0.f;
                ws[O_ERR + (size_t)to * BNO + (size_t)b * kNO + o] =
                    os_n - label[((size_t)b * kT + to) * kNO + o];
                dout[((size_t)b * kT + to) * kNO + o] = os_n;
            }
        }
    }
}

// ---- post: densify hs (rows 1..T) AND write trb (bf16 transposed trec) -----
__global__ __launch_bounds__(256) void k_post(float* __restrict__ ws,
                                              const unsigned long long* __restrict__ gmask) {
    size_t idx = (size_t)blockIdx.x * 256 + threadIdx.x;  // < BNH
    // phase 1: dense hs[t+1][b][n] (coalesced: consecutive idx = consecutive n)
    {
        int b = (int)(idx >> 9), n = (int)(idx & 511);
        int w = n >> 6, bit = n & 63;
        for (int t = 0; t < kT; t++) {
            float cur = (float)((gmask[((size_t)t * 64 + b) * 8 + w] >> bit) & 1ull);
            ws[O_HS + (size_t)(t + 1) * BNH + idx] = cur;
        }
    }
    // phase 2: trb[n][t*64+b] = bf16(trec) (coalesced: consecutive idx = consecutive b)
    {
        int n = (int)(idx >> 6), b = (int)(idx & 63);
        int w = n >> 6, bit = n & 63;
        __hip_bfloat16* trb = (__hip_bfloat16*)(ws + O_TRB);
        float v = 0.f, p = 0.f;
        for (int t = 0; t < kT; t++) {
            v = TAU * v + p;
            trb[(size_t)n * kK + t * 64 + b] = __float2bfloat16(v);
            p = (float)((gmask[((size_t)t * 64 + b) * 8 + w] >> bit) & 1ull);
        }
    }
}

// ---- reverse kappa filter of err (in place) --------------------------------
__global__ void k_errscan(float* __restrict__ ws) {
    int idx = blockIdx.x * 256 + threadIdx.x;  // < 1280
    float v = 0.f;
    for (int t = kT - 1; t >= 0; t--) {
        float* p = ws + O_ERR + (size_t)t * BNO + idx;
        v = *p + TAU_O * v;
        *p = v;
    }
}

// ---- M2: mtb[r][tb] = bf16( LR * (errf[tb,:]@w_out)[r] * hsur[tb][r] ) ------
// One block per 8 tb rows; thread handles r = tid and tid+256; writes 16B runs.
__global__ __launch_bounds__(256) void k_M2(float* __restrict__ ws,
                                            const float* __restrict__ w_out) {
    __shared__ float wo[kNO * kNH];   // 40 KB
    __shared__ float ef[8 * kNO];
    int tid = threadIdx.x;
    int tb0 = blockIdx.x * 8;
    for (int e = tid; e < kNO * kNH; e += 256) wo[e] = w_out[e];
    for (int e = tid; e < 8 * kNO; e += 256) ef[e] = ws[O_ERR + (size_t)tb0 * kNO + e];
    __syncthreads();
    unsigned short* mtb = (unsigned short*)(ws + O_MTB);
    #pragma unroll
    for (int half = 0; half < 2; half++) {
        int r = tid + half * 256;
        short8 pack;
        #pragma unroll
        for (int tbl = 0; tbl < 8; tbl++) {
            float s = 0.f;
            #pragma unroll
            for (int o = 0; o < kNO; o++) s += ef[tbl * kNO + o] * wo[o * kNH + r];
            float val = LR * s * ws[O_HSUR + (size_t)(tb0 + tbl) * kNH + r];
            __hip_bfloat16 bv = __float2bfloat16(val);
            pack[tbl] = *(short*)&bv;
        }
        *(short8*)&mtb[(size_t)r * kK + tb0] = pack;
    }
}

// ---- transposed bf16 cast: dst[n][k=6400] = bf16(src[k][n]) -----------------
__global__ void k_castT(const float* __restrict__ src, __hip_bfloat16* __restrict__ dst, int N) {
    __shared__ float tile[32][33];
    int k0 = blockIdx.x * 32, n0 = blockIdx.y * 32;
    int tx = threadIdx.x, ty = threadIdx.y;  // 32 x 8
    #pragma unroll
    for (int j = 0; j < 32; j += 8) {
        int n = n0 + tx;
        tile[ty + j][tx] = (n < N) ? src[(size_t)(k0 + ty + j) * N + n] : 0.f;
    }
    __syncthreads();
    #pragma unroll
    for (int j = 0; j < 32; j += 8) {
        int n = n0 + ty + j;
        if (n < N) dst[(size_t)n * kK + k0 + tx] = __float2bfloat16(tile[tx][ty + j]);
    }
}

// ---- bf16 MFMA NT GEMM: C[m,n] = sum_k A[m][k]*B[n][k], K=6400, splitK=4 ----
__global__ __launch_bounds__(256) void k_gemm_nt(const unsigned short* __restrict__ A,
                                                 const unsigned short* __restrict__ B,
                                                 float* __restrict__ Cpart,
                                                 int Nrows, int ldc) {
    constexpr int KC = kK / 4, BK = 64, LDT = 72;
    int bx = blockIdx.x;
    int s = bx & 3, mt = (bx >> 2) & 3, nt = bx >> 4;
    int m0 = mt * 128, n0 = nt * 128, k0 = s * KC;
    int tid = threadIdx.x;
    int wave = tid >> 6, lane = tid & 63;
    int wm = wave & 1, wn = wave >> 1;
    __shared__ unsigned short As[128 * LDT];
    __shared__ unsigned short Bs[128 * LDT];
    f32x4 acc[4][4];
    #pragma unroll
    for (int i = 0; i < 4; i++)
        #pragma unroll
        for (int j = 0; j < 4; j++) acc[i][j] = (f32x4){0.f, 0.f, 0.f, 0.f};

    for (int kb = 0; kb < KC; kb += BK) {
        int kg = k0 + kb;
        #pragma unroll
        for (int p = 0; p < 4; p++) {
            int f = tid + p * 256;
            int row = f >> 3, seg = f & 7;
            *(short8*)&As[row * LDT + seg * 8] =
                *(const short8*)&A[(size_t)(m0 + row) * kK + kg + seg * 8];
            short8 bv = {};
            if (n0 + row < Nrows)
                bv = *(const short8*)&B[(size_t)(n0 + row) * kK + kg + seg * 8];
            *(short8*)&Bs[row * LDT + seg * 8] = bv;
        }
        __syncthreads();
        #pragma unroll
        for (int h = 0; h < 2; h++) {
            int kof = h * 32 + (lane >> 4) * 8;
            short8 af[4], bf[4];
            #pragma unroll
            for (int i = 0; i < 4; i++)
                af[i] = *(short8*)&As[(wm * 64 + i * 16 + (lane & 15)) * LDT + kof];
            #pragma unroll
            for (int j = 0; j < 4; j++)
                bf[j] = *(short8*)&Bs[(wn * 64 + j * 16 + (lane & 15)) * LDT + kof];
            #pragma unroll
            for (int i = 0; i < 4; i++)
                #pragma unroll
                for (int j = 0; j < 4; j++)
                    acc[i][j] = __builtin_amdgcn_mfma_f32_16x16x32_bf16(af[i], bf[j], acc[i][j], 0, 0, 0);
        }
        __syncthreads();
    }
    float* C = Cpart + (size_t)s * kNH * ldc;
    int rbase = (lane >> 4) * 4, col = lane & 15;
    #pragma unroll
    for (int i = 0; i < 4; i++)
        #pragma unroll
        for (int j = 0; j < 4; j++) {
            int n = n0 + wn * 64 + j * 16 + col;
            #pragma unroll
            for (int r = 0; r < 4; r++) {
                int m = m0 + wm * 64 + i * 16 + rbase + r;
                C[(size_t)m * ldc + n] = acc[i][j][r];
            }
        }
}

// ---- small TN GEMM for go (M=20), fp32 -------------------------------------
__global__ __launch_bounds__(256) void k_gemmTN_go(const float* __restrict__ A,
                                                   const float* __restrict__ Bm,
                                                   float* __restrict__ Cpart) {
    int bx = blockIdx.x, tid = threadIdx.x;  // grid 64 = 8 s * 8 nt
    int s = bx & 7, nt = bx >> 3;
    int n0 = nt * 64, k0 = s * 800;
    __shared__ float As[16][64];
    __shared__ float Bs[16][64];
    int tx = tid & 15, ty = tid >> 4;
    float acc[4][4] = {};
    for (int kb = 0; kb < 800; kb += 16) {
        #pragma unroll
        for (int e = tid; e < 1024; e += 256) {
            int kk = e >> 6, c = e & 63;
            size_t gk = (size_t)(k0 + kb + kk);
            As[kk][c] = (c < kNO) ? A[gk * kNO + c] : 0.f;
            Bs[kk][c] = Bm[gk * kNH + n0 + c];
        }
        __syncthreads();
        #pragma unroll
        for (int kk = 0; kk < 16; kk++) {
            float4 av = *(const float4*)&As[kk][ty * 4];
            float4 bv = *(const float4*)&Bs[kk][tx * 4];
            float aa[4] = {av.x, av.y, av.z, av.w};
            float bb[4] = {bv.x, bv.y, bv.z, bv.w};
            #pragma unroll
            for (int a = 0; a < 4; a++)
                #pragma unroll
                for (int c = 0; c < 4; c++) acc[a][c] += aa[a] * bb[c];
        }
        __syncthreads();
    }
    float* Cs = Cpart + (size_t)s * kNO * kNH;
    #pragma unroll
    for (int a = 0; a < 4; a++) {
        int m = ty * 4 + a;
        if (m >= kNO) continue;
        #pragma unroll
        for (int c = 0; c < 4; c++)
            Cs[(size_t)m * kNH + n0 + tx * 4 + c] = acc[a][c];
    }
}

// ---- merged reduction: gf (4 slices), gr (4 slices), go (8 slices) ----------
__global__ void k_reduce_all(const float* __restrict__ ws, float* __restrict__ dout) {
    int idx = blockIdx.x * 256 + threadIdx.x;  // < 630784
    const int NGF = kNH * kNI, NGR = kNH * kNH, NGO = kNO * kNH;
    float s = 0.f;
    if (idx < NGF) {
        int m = idx / kNI, n = idx - m * kNI;
        size_t src = O_PGF + (size_t)m * 768 + n;
        #pragma unroll
        for (int k = 0; k < 4; k++) s += ws[src + (size_t)k * kNH * 768];
        dout[OUT_GF + idx] = s;   // LR folded into mtb
    } else if (idx < NGF + NGR) {
        int j = idx - NGF;
        #pragma unroll
        for (int k = 0; k < 4; k++) s += ws[O_PGR + j + (size_t)k * NGR];
        dout[OUT_GR + j] = s;
    } else if (idx < NGF + NGR + NGO) {
        int j = idx - NGF - NGR;
        #pragma unroll
        for (int k = 0; k < 8; k++) s += ws[O_PGO + (size_t)k * NGO + j];
        dout[OUT_GO + j] = LR * s;
    }
}

extern "C" void kernel_launch(void* const* d_in, const int* in_sizes, int n_in,
                              void* d_out, int out_size, void* d_ws, size_t ws_size,
                              hipStream_t stream) {
    (void)in_sizes; (void)n_in; (void)out_size;
    const float* x     = (const float*)d_in[0];
    const float* label = (const float*)d_in[1];
    const float* w_fc1 = (const float*)d_in[3];
    const float* w_rec = (const float*)d_in[4];
    const float* w_out = (const float*)d_in[5];
    float* out = (float*)d_out;
    float* ws  = (float*)d_ws;

    if (ws_size < WS_FLOATS * sizeof(float)) return;

    __hip_bfloat16* mtb = (__hip_bfloat16*)(ws + O_MTB);
    __hip_bfloat16* trb = (__hip_bfloat16*)(ws + O_TRB);
    __hip_bfloat16* tib = (__hip_bfloat16*)(ws + O_TIB);
    unsigned long long* gmask = (unsigned long long*)(ws + O_MSK);

    k_transpose<<<dim3(22, 16), dim3(32, 8), 0, stream>>>(w_fc1, ws + O_WT);
    k_tin<<<175, 256, 0, stream>>>(x, ws + O_TIN);
    k_xw2<<<200, 256, 0, stream>>>(x, ws + O_WT, ws + O_XW);

    k_forward<<<kB, 832, 0, stream>>>(ws, label, w_rec, w_out, out, gmask);

    k_post<<<128, 256, 0, stream>>>(ws, gmask);     // dense hs + trb
    k_errscan<<<5, 256, 0, stream>>>(ws);
    k_M2<<<kT * kB / 8, 256, 0, stream>>>(ws, w_out);       // reads HSUR, writes mtb
    k_castT<<<dim3(200, 22), dim3(32, 8), 0, stream>>>(ws + O_TIN, tib, kNI);  // after k_M2 (tib overlays HSUR)

    k_gemm_nt<<<96, 256, 0, stream>>>((const unsigned short*)mtb, (const unsigned short*)tib,
                                      ws + O_PGF, kNI, 768);
    k_gemm_nt<<<64, 256, 0, stream>>>((const unsigned short*)mtb, (const unsigned short*)trb,
                                      ws + O_PGR, kNH, kNH);
    k_gemmTN_go<<<64, 256, 0, stream>>>(ws + O_ERR, ws + O_HS + BNH, ws + O_PGO);

    k_reduce_all<<<2464, 256, 0, stream>>>(ws, out);
}

// Round 8
// 774.206 us; speedup vs baseline: 1.0380x; 1.0380x over previous
//
#include <hip/hip_runtime.h>
#include <hip/hip_bf16.h>

// Problem constants (B,T,NI,NH,NO fixed by the reference)
constexpr int kB  = 64;
constexpr int kT  = 100;
constexpr int kNI = 700;
constexpr int kNH = 512;
constexpr int kNO = 20;
constexpr float TAU   = 0.6f;
constexpr float TAU_O = 0.6f;
constexpr float THR   = 0.6f;
constexpr float LR    = 0.05f;

constexpr size_t BNH = (size_t)kB * kNH;   // 32768
constexpr size_t BNI = (size_t)kB * kNI;   // 44800
constexpr size_t BNO = (size_t)kB * kNO;   // 1280
constexpr int kK   = kT * kB;              // 6400 (grad-GEMM K)
constexpr int kKP  = 704;                  // padded K for xw GEMM

typedef __attribute__((ext_vector_type(8))) short short8;
typedef __attribute__((ext_vector_type(4))) float f32x4;

// ---------------- workspace layout (float offsets) ---------------------------
// XW dead after k_forward -> PGF/PGR/PGO overlay it.
// HSUR dead after k_forward tail -> TIB overlays it (k_post_cast runs after).
constexpr size_t O_XW   = 0;                                // [T, t*64+b, NH] 3,276,800
constexpr size_t O_PGF  = 0;                                // 4 x [512][768] = 1,572,864
constexpr size_t O_PGR  = 1572864;                          // 4 x [512][512] = 1,048,576
constexpr size_t O_PGO  = 2621440;                          // 8 x [20][512]  = 81,920
constexpr size_t O_HSUR = 3276800;                          // [T,B,NH] 3,276,800
constexpr size_t O_TIB  = 3276800;                          // bf16 [700][6400] = 2,240,000 fl
constexpr size_t O_TIN  = 6553600;                          // [T,B,NI] 4,480,000
constexpr size_t O_HS   = 11033600;                         // [T+1,B,NH] (row t = hs_{t-1})
constexpr size_t O_ERR  = 14343168;                         // [T,B,NO] errf 128,000
constexpr size_t O_WT   = 14471168;                         // [704,512] 360,448
constexpr size_t O_MTB  = 14831616;                         // bf16 [512][6400]
constexpr size_t O_TRB  = 16470016;                         // bf16 [512][6400]
constexpr size_t O_MSK  = 18108416;                         // u64 [T][B][8]
constexpr size_t WS_FLOATS = 18210816;                      // ~72.8 MB

// d_out layout
constexpr size_t OUT_GF = (size_t)kB * kT * kNO;
constexpr size_t OUT_GR = OUT_GF + (size_t)kNH * kNI;
constexpr size_t OUT_GO = OUT_GR + (size_t)kNH * kNH;

// ---- merged prep: blocks 0..351 transpose w_fc1 -> wT; blocks 352.. tin scan
__global__ __launch_bounds__(256) void k_prep(const float* __restrict__ w,
                                              const float* __restrict__ x,
                                              float* __restrict__ wT,
                                              float* __restrict__ tin) {
    int bx = blockIdx.x, tid = threadIdx.x;
    if (bx < 352) {
        __shared__ float tile[32][33];
        int i0 = (bx % 22) * 32, r0 = (bx / 22) * 32;
        int tx = tid & 31, ty = tid >> 5;  // 32 x 8
        #pragma unroll
        for (int k = 0; k < 32; k += 8) {
            int i = i0 + tx;
            tile[ty + k][tx] = (i < kNI) ? w[(size_t)(r0 + ty + k) * kNI + i] : 0.f;
        }
        __syncthreads();
        #pragma unroll
        for (int k = 0; k < 32; k += 8) {
            int i = i0 + ty + k;
            wT[(size_t)i * kNH + r0 + tx] = tile[tx][ty + k];
        }
    } else {
        int idx = (bx - 352) * 256 + tid;   // < B*NI
        int b = idx / kNI, i = idx % kNI;
        const float* xp = x + (size_t)b * kT * kNI + i;
        float v = 0.f;
        for (int t = 0; t < kT; t++) {
            v = TAU * v + xp[(size_t)t * kNI];
            tin[(size_t)t * BNI + idx] = v;
        }
    }
}

// ---- XW = Xperm @ wT : C[m=t*64+b, n<512], K=704 (fp32, exact) --------------
__global__ __launch_bounds__(256) void k_xw2(const float* __restrict__ x,
                                             const float* __restrict__ wT,
                                             float* __restrict__ XW) {
    int bx = blockIdx.x;
    int mt = bx % 50, nt = bx / 50;
    int m0 = mt * 128, n0 = nt * 128;
    int tid = threadIdx.x, tx = tid & 15, ty = tid >> 4;
    __shared__ float As[128][20];
    __shared__ float Bs[16][128];
    float acc[8][8] = {};
    int arow = tid >> 1, ahalf = tid & 1;
    int bb = (m0 + arow) & 63, tt = (m0 + arow) >> 6;
    const float* ap = x + ((size_t)bb * kT + tt) * kNI;
    for (int k0 = 0; k0 < kKP; k0 += 16) {
        #pragma unroll
        for (int u = 0; u < 2; u++) {
            int k = k0 + ahalf * 8 + u * 4;
            float4 v = (k + 3 < kNI) ? *(const float4*)(ap + k)
                                     : make_float4(0.f, 0.f, 0.f, 0.f);
            *(float4*)&As[arow][ahalf * 8 + u * 4] = v;
        }
        #pragma unroll
        for (int u = 0; u < 2; u++) {
            int f = tid * 2 + u;
            int kk = f >> 5, c4 = f & 31;
            *(float4*)&Bs[kk][c4 * 4] =
                *(const float4*)(wT + (size_t)(k0 + kk) * kNH + n0 + c4 * 4);
        }
        __syncthreads();
        #pragma unroll
        for (int kk = 0; kk < 16; kk++) {
            float av[8];
            #pragma unroll
            for (int i = 0; i < 4; i++) {
                av[i]     = As[ty * 4 + i][kk];
                av[4 + i] = As[64 + ty * 4 + i][kk];
            }
            float4 b0 = *(const float4*)&Bs[kk][tx * 4];
            float4 b1 = *(const float4*)&Bs[kk][64 + tx * 4];
            float bvv[8] = {b0.x, b0.y, b0.z, b0.w, b1.x, b1.y, b1.z, b1.w};
            #pragma unroll
            for (int i = 0; i < 8; i++)
                #pragma unroll
                for (int j = 0; j < 8; j++) acc[i][j] += av[i] * bvv[j];
        }
        __syncthreads();
    }
    #pragma unroll
    for (int i = 0; i < 8; i++) {
        int m = m0 + ((i < 4) ? (ty * 4 + i) : (64 + ty * 4 + i - 4));
        float* dst = XW + (size_t)m * kNH + n0;
        *(float4*)(dst + tx * 4)      = make_float4(acc[i][0], acc[i][1], acc[i][2], acc[i][3]);
        *(float4*)(dst + 64 + tx * 4) = make_float4(acc[i][4], acc[i][5], acc[i][6], acc[i][7]);
    }
}

// ---- fused forward: ONE block of 832 threads (13 waves) per sample ----------
// Waves 0-7: gather (R6 structure — data-BW bound, simple ctz walk).
// Waves 8-12: output LIF layer one step behind; err history kept in LDS.
// Tail: in-block reverse kappa scan of err -> errf (global, for go GEMM)
//       + direct production of mtb (bf16 M^T) -> kills k_errscan & k_M2.
__global__ __launch_bounds__(832) void k_forward(float* __restrict__ ws,
                                                 const float* __restrict__ label,
                                                 const float* __restrict__ w_rec,
                                                 const float* __restrict__ w_out,
                                                 float* __restrict__ dout,
                                                 unsigned long long* __restrict__ gmask) {
    __shared__ float wout_ld[kNO * kNH];          // 40 KB
    __shared__ float partial[8][kNH];             // 16 KB
    __shared__ unsigned long long mh[kT * 8];     // 6.4 KB mask history
    __shared__ float errh[kT * kNO];              // 8 KB err/errf history

    int b = blockIdx.x, tid = threadIdx.x;
    int wave = tid >> 6, lane = tid & 63;
    const f32x4* wr4 = (const f32x4*)w_rec;
    for (int e = tid; e < kNO * kNH; e += 832) wout_ld[e] = w_out[e];
    float hm = 0.f, sp_prev = 0.f;
    float om_r[4] = {0.f, 0.f, 0.f, 0.f}, os_r[4] = {0.f, 0.f, 0.f, 0.f};
    int q = wave - 8;
    const int coff = lane * 2;
    __syncthreads();

    for (int t = 0; t < kT; t++) {
        float xw = 0.f;
        if (wave < 8) {
            xw = ws[O_XW + ((size_t)t * 64 + b) * kNH + tid];
            unsigned long long m = (t > 0) ? mh[(t - 1) * 8 + wave] : 0ull;
            const size_t base = (size_t)wave * 64;
            f32x4 s0 = {0.f, 0.f, 0.f, 0.f}, s1 = s0;
            while (m) {
                int j = __builtin_ctzll(m); m &= m - 1;
                const f32x4* r = wr4 + (base + j) * 128 + coff;
                s0 += r[0]; s1 += r[1];
            }
            *(f32x4*)&partial[wave][lane * 8]     = s0;
            *(f32x4*)&partial[wave][lane * 8 + 4] = s1;
        } else if (t > 0) {
            // output LIF layer for step t-1 (wave q = 0..4)
            int to = t - 1;
            unsigned long long mk[8];
            #pragma unroll
            for (int k = 0; k < 8; k++) mk[k] = mh[to * 8 + k];
            #pragma unroll
            for (int r = 0; r < 4; r++) {
                int o = q * 4 + r;
                float p = 0.f;
                #pragma unroll
                for (int k = 0; k < 8; k++)
                    if ((mk[k] >> lane) & 1) p += wout_ld[o * kNH + 64 * k + lane];
                #pragma unroll
                for (int off = 32; off >= 1; off >>= 1) p += __shfl_xor(p, off);
                if (lane == 0) {
                    float om_n = TAU * om_r[r] * (1.f - os_r[r]) + p;
                    float os_n = (om_n >= THR) ? 1.f : 0.f;
                    om_r[r] = om_n; os_r[r] = os_n;
                    errh[to * kNO + o] = os_n - label[((size_t)b * kT + to) * kNO + o];
                    dout[((size_t)b * kT + to) * kNO + o] = os_n;
                }
            }
        }
        __syncthreads();
        // ---- B: LIF update (threads < 512) ----
        if (tid < kNH) {
            float rec = ((partial[0][tid] + partial[1][tid]) + (partial[2][tid] + partial[3][tid]))
                      + ((partial[4][tid] + partial[5][tid]) + (partial[6][tid] + partial[7][tid]));
            hm = TAU * hm * (1.f - sp_prev) + (xw + rec);
            bool v = (hm >= THR);
            float sp = v ? 1.f : 0.f;
            sp_prev = sp;
            ws[O_HSUR + (size_t)t * BNH + (size_t)b * kNH + tid] =
                TAU * fmaxf(0.f, 1.f - fabsf(hm - THR) * (1.f / THR));
            unsigned long long bal = __ballot(v);
            if (lane == 0) {
                mh[t * 8 + wave] = bal;
                gmask[((size_t)t * 64 + b) * 8 + wave] = bal;
            }
        }
        __syncthreads();
    }
    // ---- tail 1: output layer for t = 99 ----
    if (wave >= 8) {
        int to = kT - 1;
        unsigned long long mk[8];
        #pragma unroll
        for (int k = 0; k < 8; k++) mk[k] = mh[to * 8 + k];
        #pragma unroll
        for (int r = 0; r < 4; r++) {
            int o = q * 4 + r;
            float p = 0.f;
            #pragma unroll
            for (int k = 0; k < 8; k++)
                if ((mk[k] >> lane) & 1) p += wout_ld[o * kNH + 64 * k + lane];
            #pragma unroll
            for (int off = 32; off >= 1; off >>= 1) p += __shfl_xor(p, off);
            if (lane == 0) {
                float om_n = TAU * om_r[r] * (1.f - os_r[r]) + p;
                float os_n = (om_n >= THR) ? 1.f : 0.f;
                errh[to * kNO + o] = os_n - label[((size_t)b * kT + to) * kNO + o];
                dout[((size_t)b * kT + to) * kNO + o] = os_n;
            }
        }
    }
    __syncthreads();
    // ---- tail 2: reverse kappa scan (in LDS) + errf -> global for go GEMM ----
    if (wave == 8 && lane < kNO) {
        float v = 0.f;
        for (int t = kT - 1; t >= 0; t--) {
            v = errh[t * kNO + lane] + TAU_O * v;
            errh[t * kNO + lane] = v;
            ws[O_ERR + (size_t)t * BNO + (size_t)b * kNO + lane] = v;
        }
    }
    __syncthreads();
    // ---- tail 3: mtb[r][t*64+b] = bf16( LR*(errf@w_out)[r]*hsur[t][b][r] ) ---
    if (tid < kNH) {
        unsigned short* mtb = (unsigned short*)(ws + O_MTB);
        for (int t = 0; t < kT; t++) {
            float s = 0.f;
            #pragma unroll
            for (int o = 0; o < kNO; o++) s += errh[t * kNO + o] * wout_ld[o * kNH + tid];
            float val = LR * s * ws[O_HSUR + (size_t)t * BNH + (size_t)b * kNH + tid];
            __hip_bfloat16 bv = __float2bfloat16(val);
            mtb[(size_t)tid * kK + t * 64 + b] = *(unsigned short*)&bv;
        }
    }
}

// ---- merged post: blocks 0..127 densify hs + trb; blocks 128.. castT(tin) --
__global__ __launch_bounds__(256) void k_post_cast(float* __restrict__ ws,
                                                   const unsigned long long* __restrict__ gmask) {
    int bx = blockIdx.x, tid = threadIdx.x;
    if (bx < 128) {
        size_t idx = (size_t)bx * 256 + tid;  // < BNH
        {   // dense hs[t+1][b][n]
            int b = (int)(idx >> 9), n = (int)(idx & 511);
            int w = n >> 6, bit = n & 63;
            for (int t = 0; t < kT; t++) {
                float cur = (float)((gmask[((size_t)t * 64 + b) * 8 + w] >> bit) & 1ull);
                ws[O_HS + (size_t)(t + 1) * BNH + idx] = cur;
            }
        }
        {   // trb[n][t*64+b] = bf16(trec)
            int n = (int)(idx >> 6), b = (int)(idx & 63);
            int w = n >> 6, bit = n & 63;
            __hip_bfloat16* trb = (__hip_bfloat16*)(ws + O_TRB);
            float v = 0.f, p = 0.f;
            for (int t = 0; t < kT; t++) {
                v = TAU * v + p;
                trb[(size_t)n * kK + t * 64 + b] = __float2bfloat16(v);
                p = (float)((gmask[((size_t)t * 64 + b) * 8 + w] >> bit) & 1ull);
            }
        }
    } else {
        // castT: tib[n][k] = bf16(tin[k][n]), n < 700, k < 6400
        __shared__ float tile[32][33];
        int v = bx - 128;                    // 0..4399 (200 x 22)
        int k0 = (v % 200) * 32, n0 = (v / 200) * 32;
        int tx = tid & 31, ty = tid >> 5;    // 32 x 8
        const float* src = ws + O_TIN;
        __hip_bfloat16* dst = (__hip_bfloat16*)(ws + O_TIB);
        #pragma unroll
        for (int j = 0; j < 32; j += 8) {
            int n = n0 + tx;
            tile[ty + j][tx] = (n < kNI) ? src[(size_t)(k0 + ty + j) * kNI + n] : 0.f;
        }
        __syncthreads();
        #pragma unroll
        for (int j = 0; j < 32; j += 8) {
            int n = n0 + ty + j;
            if (n < kNI) dst[(size_t)n * kK + k0 + tx] = __float2bfloat16(tile[tx][ty + j]);
        }
    }
}

// ---- bf16 MFMA NT GEMM: C[m,n] = sum_k A[m][k]*B[n][k], K=6400, splitK=4 ----
__global__ __launch_bounds__(256) void k_gemm_nt(const unsigned short* __restrict__ A,
                                                 const unsigned short* __restrict__ B,
                                                 float* __restrict__ Cpart,
                                                 int Nrows, int ldc) {
    constexpr int KC = kK / 4, BK = 64, LDT = 72;
    int bx = blockIdx.x;
    int s = bx & 3, mt = (bx >> 2) & 3, nt = bx >> 4;
    int m0 = mt * 128, n0 = nt * 128, k0 = s * KC;
    int tid = threadIdx.x;
    int wave = tid >> 6, lane = tid & 63;
    int wm = wave & 1, wn = wave >> 1;
    __shared__ unsigned short As[128 * LDT];
    __shared__ unsigned short Bs[128 * LDT];
    f32x4 acc[4][4];
    #pragma unroll
    for (int i = 0; i < 4; i++)
        #pragma unroll
        for (int j = 0; j < 4; j++) acc[i][j] = (f32x4){0.f, 0.f, 0.f, 0.f};

    for (int kb = 0; kb < KC; kb += BK) {
        int kg = k0 + kb;
        #pragma unroll
        for (int p = 0; p < 4; p++) {
            int f = tid + p * 256;
            int row = f >> 3, seg = f & 7;
            *(short8*)&As[row * LDT + seg * 8] =
                *(const short8*)&A[(size_t)(m0 + row) * kK + kg + seg * 8];
            short8 bv = {};
            if (n0 + row < Nrows)
                bv = *(const short8*)&B[(size_t)(n0 + row) * kK + kg + seg * 8];
            *(short8*)&Bs[row * LDT + seg * 8] = bv;
        }
        __syncthreads();
        #pragma unroll
        for (int h = 0; h < 2; h++) {
            int kof = h * 32 + (lane >> 4) * 8;
            short8 af[4], bf[4];
            #pragma unroll
            for (int i = 0; i < 4; i++)
                af[i] = *(short8*)&As[(wm * 64 + i * 16 + (lane & 15)) * LDT + kof];
            #pragma unroll
            for (int j = 0; j < 4; j++)
                bf[j] = *(short8*)&Bs[(wn * 64 + j * 16 + (lane & 15)) * LDT + kof];
            #pragma unroll
            for (int i = 0; i < 4; i++)
                #pragma unroll
                for (int j = 0; j < 4; j++)
                    acc[i][j] = __builtin_amdgcn_mfma_f32_16x16x32_bf16(af[i], bf[j], acc[i][j], 0, 0, 0);
        }
        __syncthreads();
    }
    float* C = Cpart + (size_t)s * kNH * ldc;
    int rbase = (lane >> 4) * 4, col = lane & 15;
    #pragma unroll
    for (int i = 0; i < 4; i++)
        #pragma unroll
        for (int j = 0; j < 4; j++) {
            int n = n0 + wn * 64 + j * 16 + col;
            #pragma unroll
            for (int r = 0; r < 4; r++) {
                int m = m0 + wm * 64 + i * 16 + rbase + r;
                C[(size_t)m * ldc + n] = acc[i][j][r];
            }
        }
}

// ---- small TN GEMM for go (M=20), fp32 -------------------------------------
__global__ __launch_bounds__(256) void k_gemmTN_go(const float* __restrict__ A,
                                                   const float* __restrict__ Bm,
                                                   float* __restrict__ Cpart) {
    int bx = blockIdx.x, tid = threadIdx.x;  // grid 64 = 8 s * 8 nt
    int s = bx & 7, nt = bx >> 3;
    int n0 = nt * 64, k0 = s * 800;
    __shared__ float As[16][64];
    __shared__ float Bs[16][64];
    int tx = tid & 15, ty = tid >> 4;
    float acc[4][4] = {};
    for (int kb = 0; kb < 800; kb += 16) {
        #pragma unroll
        for (int e = tid; e < 1024; e += 256) {
            int kk = e >> 6, c = e & 63;
            size_t gk = (size_t)(k0 + kb + kk);
            As[kk][c] = (c < kNO) ? A[gk * kNO + c] : 0.f;
            Bs[kk][c] = Bm[gk * kNH + n0 + c];
        }
        __syncthreads();
        #pragma unroll
        for (int kk = 0; kk < 16; kk++) {
            float4 av = *(const float4*)&As[kk][ty * 4];
            float4 bv = *(const float4*)&Bs[kk][tx * 4];
            float aa[4] = {av.x, av.y, av.z, av.w};
            float bb[4] = {bv.x, bv.y, bv.z, bv.w};
            #pragma unroll
            for (int a = 0; a < 4; a++)
                #pragma unroll
                for (int c = 0; c < 4; c++) acc[a][c] += aa[a] * bb[c];
        }
        __syncthreads();
    }
    float* Cs = Cpart + (size_t)s * kNO * kNH;
    #pragma unroll
    for (int a = 0; a < 4; a++) {
        int m = ty * 4 + a;
        if (m >= kNO) continue;
        #pragma unroll
        for (int c = 0; c < 4; c++)
            Cs[(size_t)m * kNH + n0 + tx * 4 + c] = acc[a][c];
    }
}

// ---- merged reduction: gf (4 slices), gr (4 slices), go (8 slices) ----------
__global__ void k_reduce_all(const float* __restrict__ ws, float* __restrict__ dout) {
    int idx = blockIdx.x * 256 + threadIdx.x;  // < 630784
    const int NGF = kNH * kNI, NGR = kNH * kNH, NGO = kNO * kNH;
    float s = 0.f;
    if (idx < NGF) {
        int m = idx / kNI, n = idx - m * kNI;
        size_t src = O_PGF + (size_t)m * 768 + n;
        #pragma unroll
        for (int k = 0; k < 4; k++) s += ws[src + (size_t)k * kNH * 768];
        dout[OUT_GF + idx] = s;   // LR folded into mtb
    } else if (idx < NGF + NGR) {
        int j = idx - NGF;
        #pragma unroll
        for (int k = 0; k < 4; k++) s += ws[O_PGR + j + (size_t)k * NGR];
        dout[OUT_GR + j] = s;
    } else if (idx < NGF + NGR + NGO) {
        int j = idx - NGF - NGR;
        #pragma unroll
        for (int k = 0; k < 8; k++) s += ws[O_PGO + (size_t)k * NGO + j];
        dout[OUT_GO + j] = LR * s;
    }
}

extern "C" void kernel_launch(void* const* d_in, const int* in_sizes, int n_in,
                              void* d_out, int out_size, void* d_ws, size_t ws_size,
                              hipStream_t stream) {
    (void)in_sizes; (void)n_in; (void)out_size;
    const float* x     = (const float*)d_in[0];
    const float* label = (const float*)d_in[1];
    const float* w_fc1 = (const float*)d_in[3];
    const float* w_rec = (const float*)d_in[4];
    const float* w_out = (const float*)d_in[5];
    float* out = (float*)d_out;
    float* ws  = (float*)d_ws;

    if (ws_size < WS_FLOATS * sizeof(float)) return;

    __hip_bfloat16* mtb = (__hip_bfloat16*)(ws + O_MTB);
    __hip_bfloat16* trb = (__hip_bfloat16*)(ws + O_TRB);
    __hip_bfloat16* tib = (__hip_bfloat16*)(ws + O_TIB);
    unsigned long long* gmask = (unsigned long long*)(ws + O_MSK);

    k_prep<<<527, 256, 0, stream>>>(w_fc1, x, ws + O_WT, ws + O_TIN);
    k_xw2<<<200, 256, 0, stream>>>(x, ws + O_WT, ws + O_XW);

    k_forward<<<kB, 832, 0, stream>>>(ws, label, w_rec, w_out, out, gmask);

    k_post_cast<<<4528, 256, 0, stream>>>(ws, gmask);   // hs + trb + tib

    k_gemm_nt<<<96, 256, 0, stream>>>((const unsigned short*)mtb, (const unsigned short*)tib,
                                      ws + O_PGF, kNI, 768);
    k_gemm_nt<<<64, 256, 0, stream>>>((const unsigned short*)mtb, (const unsigned short*)trb,
                                      ws + O_PGR, kNH, kNH);
    k_gemmTN_go<<<64, 256, 0, stream>>>(ws + O_ERR, ws + O_HS + BNH, ws + O_PGO);

    k_reduce_all<<<2464, 256, 0, stream>>>(ws, out);
}